// Round 13
// baseline (53.568 us; speedup 1.0000x reference)
//
#include <hip/hip_runtime.h>

// Problem constants (UserContextAttentionPooler): U=128, I=256, J=512, C=E=128
#define UU 128
#define II 256
#define JJ 512
#define CC 128
#define EE 128
#define IB2 32           // i-rows per block (2 MFMA tiles)
#define NIB2 8           // i-blocks per u
#define JT 64            // j per V tile
#define NJT 8            // V tiles per u
#define VTP 72           // (fallback kernel) Vt row stride in shorts
#define IBF 16           // fallback i-rows per block

typedef short bf16x8 __attribute__((ext_vector_type(8)));
typedef float f32x4 __attribute__((ext_vector_type(4)));

union FragU { bf16x8 v; unsigned u[4]; };

__device__ __forceinline__ float fast_tanh(float x) {
    float ex = __expf(2.0f * x);
    return 1.0f - 2.0f / (ex + 1.0f);
}

__device__ __forceinline__ unsigned pack_bf16x2(float lo, float hi) {
    unsigned ul = __float_as_uint(lo), uh = __float_as_uint(hi);
    ul = (ul + 0x7FFFu + ((ul >> 16) & 1u)) >> 16;
    uh = (uh + 0x7FFFu + ((uh >> 16) & 1u)) >> 16;
    return ul | (uh << 16);
}

__device__ __forceinline__ short bf16s(float f) {
    unsigned u = __float_as_uint(f);
    u = (u + 0x7FFFu + ((u >> 16) & 1u)) >> 16;
    return (short)u;
}

__device__ __forceinline__ float wave_reduce_add(float v) {
#pragma unroll
    for (int k = 32; k >= 1; k >>= 1) v += __shfl_xor(v, k, 64);
    return v;
}

// ---------------------------------------------------------------------------
// Kernel A: grid EXACTLY 1024 (one co-residency round at 4 blocks/CU).
// Every block does one VT tile (vt_g bf16 B-tile + s_k; itc read once,
// nontemporal; writer XCD == consumer XCD == u%8). Blocks 0-63 additionally
// fold in the u_part chunk; block 64 folds in the wt_g pack.
// Vt tile (u,jt), short idx: kk*4096 + c*32 + (j&31).
// ---------------------------------------------------------------------------
#define PRE_BLOCKS (UU * NJT)     // 1024

__global__ void precompute_kernel(const float* __restrict__ itc,
                                  const float* __restrict__ user,
                                  const float* __restrict__ wd,
                                  const float* __restrict__ Wm,
                                  const float* __restrict__ bm,
                                  float* __restrict__ sk_g,
                                  float* __restrict__ up_g,
                                  short* __restrict__ vtg,
                                  short* __restrict__ wtg) {
    __shared__ float vt_f[JT][CC + 4];
    int b = blockIdx.x;
    int t = threadIdx.x;
    // ---- VT tile (all blocks) ----
    {
        int u = b & 127, jt = b >> 7;   // u fast -> writer XCD = u%8
        const float* src = itc + ((size_t)u * JJ + jt * JT) * CC;
#pragma unroll
        for (int k = 0; k < 8; ++k) {
            int f = t + 256 * k;
            int row = f >> 5, c4 = (f & 31) * 4;
            f32x4 v = __builtin_nontemporal_load(
                (const f32x4*)&src[(size_t)row * CC + c4]);
            *(f32x4*)&vt_f[row][c4] = v;
        }
        __syncthreads();
        // s_k for these 64 rows (4 threads per row)
        {
            int r = t >> 2, q4 = t & 3;
            float s = 0.f;
#pragma unroll
            for (int cc = 0; cc < 32; cc += 4) {
                float4 a = *(const float4*)&vt_f[r][q4 * 32 + cc];
                float4 w = *(const float4*)&wd[CC + q4 * 32 + cc];
                s += a.x * w.x + a.y * w.y + a.z * w.z + a.w * w.w;
            }
            s += __shfl_xor(s, 1, 64);
            s += __shfl_xor(s, 2, 64);
            if (q4 == 0) sk_g[u * JJ + jt * JT + r] = s;
        }
        // pack transposed bf16 tile: [kk][c][j&31], 16B stores
        {
            int c = t & 127, half = t >> 7;
            unsigned* dst = (unsigned*)(vtg + (size_t)(u * NJT + jt) * 8192) +
                            half * 2048 + c * 16;
#pragma unroll
            for (int m4 = 0; m4 < 4; ++m4) {
                unsigned q[4];
#pragma unroll
                for (int mm = 0; mm < 4; ++mm) {
                    int m = 4 * m4 + mm;
                    q[mm] = pack_bf16x2(vt_f[32 * half + 2 * m][c],
                                        vt_f[32 * half + 2 * m + 1][c]);
                }
                *(uint4*)&dst[4 * m4] = make_uint4(q[0], q[1], q[2], q[3]);
            }
        }
    }
    // ---- fold-in: u_part chunk (blocks 0-63) ----
    if (b < 64) {
        int idx = b * 256 + t;          // covers U*C = 16384
        int uu = idx >> 7, c = idx & 127;
        float acc = bm[c];
#pragma unroll 8
        for (int e = 0; e < EE; ++e) acc += user[uu * EE + e] * Wm[e * CC + c];
        up_g[idx] = acc;
    } else if (b == 64) {
        // ---- fold-in: pack W_mlp[E:] (128x128) -> wt_g, B-frag order ----
        int n = t & 127, khalf = t >> 7;
#pragma unroll
        for (int ks2 = 0; ks2 < 2; ++ks2) {
            int ks = khalf * 2 + ks2;
#pragma unroll
            for (int g = 0; g < 4; ++g) {
                unsigned q[4];
#pragma unroll
                for (int pr = 0; pr < 4; ++pr) {
                    float lo = Wm[(size_t)(EE + 32 * ks + 8 * g + 2 * pr) * CC + n];
                    float hi = Wm[(size_t)(EE + 32 * ks + 8 * g + 2 * pr + 1) * CC + n];
                    q[pr] = pack_bf16x2(lo, hi);
                }
                *(uint4*)&wtg[ks * 4096 + n * 32 + 8 * g] =
                    make_uint4(q[0], q[1], q[2], q[3]);
            }
        }
    }
}

// ---------------------------------------------------------------------------
// Kernel B (main, R11 structure; stores switched NT->normal so the tail can
// linger dirty in L2 past kernel end): one block per (u, 32-row i-slab) =
// 2 MFMA tiles sharing each B-fragment. 256 threads = 4 waves, 4 blocks/CU.
// All loads issued before the attn store burst.
// ---------------------------------------------------------------------------
__global__ __launch_bounds__(256, 4) void fused_main(
    const float* __restrict__ tgt, const int* __restrict__ mask,
    const float* __restrict__ wd, const float* __restrict__ bd,
    const float* __restrict__ sk_g, const float* __restrict__ up_g,
    const short* __restrict__ vt_g, const short* __restrict__ wt_g,
    float* __restrict__ out_ctx, float* __restrict__ out_attn) {
    __shared__ __align__(16) short ps[16384];  // 32KB: 2 swizzled p tiles
    __shared__ float dinv_lds[IB2];

    int b = blockIdx.x;
    int x = b & 7, q = b >> 3;
    int u = x + 8 * (q >> 3);      // 8 blocks of a given u -> same XCD
    int ib = q & 7;
    int i0 = ib * IB2;
    int t = threadIdx.x;
    int w = t >> 6, l = t & 63, ln = l & 15, g = l >> 4;
    int r2 = t >> 3, seg8 = t & 7;  // phase0/1: row [0,32), col-segment [0,8)
    int tile = r2 >> 4, rr = r2 & 15;

    // ---- Phase 0: s_t for row r2 (8 threads/row, 16 floats each; nt) ----
    float sv;
    {
        const float* trow = tgt + ((size_t)(u * II + i0 + r2)) * CC + seg8 * 16;
        f32x4 t0 = __builtin_nontemporal_load((const f32x4*)&trow[0]);
        f32x4 t1 = __builtin_nontemporal_load((const f32x4*)&trow[4]);
        f32x4 t2 = __builtin_nontemporal_load((const f32x4*)&trow[8]);
        f32x4 t3 = __builtin_nontemporal_load((const f32x4*)&trow[12]);
        float4 w0 = *(const float4*)&wd[seg8 * 16];
        float4 w1 = *(const float4*)&wd[seg8 * 16 + 4];
        float4 w2 = *(const float4*)&wd[seg8 * 16 + 8];
        float4 w3 = *(const float4*)&wd[seg8 * 16 + 12];
        float part = t0[0] * w0.x + t0[1] * w0.y + t0[2] * w0.z + t0[3] * w0.w +
                     t1[0] * w1.x + t1[1] * w1.y + t1[2] * w1.z + t1[3] * w1.w +
                     t2[0] * w2.x + t2[1] * w2.y + t2[2] * w2.z + t2[3] * w2.w +
                     t3[0] * w3.x + t3[1] * w3.y + t3[2] * w3.z + t3[3] * w3.w;
        part += __shfl_xor(part, 1, 64);
        part += __shfl_xor(part, 2, 64);
        part += __shfl_xor(part, 4, 64);
        sv = part + bd[0];
    }

    // ---- Phase 1: p; thread handles 64 elems of row r2 ----
    const float* skb = sk_g + u * JJ;
    const int* mkb = mask + u * JJ;
    char* psrow = (char*)ps + tile * 16384 + rr * 1024;
    float rowsum = 0.f;
#pragma unroll 4
    for (int h = 0; h < 8; ++h) {
        int gcol = seg8 + 8 * h;
        int jb = gcol * 8;
        float4 k0 = *(const float4*)&skb[jb];
        float4 k1 = *(const float4*)&skb[jb + 4];
        int4 m0 = *(const int4*)&mkb[jb];
        int4 m1 = *(const int4*)&mkb[jb + 4];
        float p0 = m0.x ? __expf(fast_tanh(sv + k0.x)) : 0.f;
        float p1 = m0.y ? __expf(fast_tanh(sv + k0.y)) : 0.f;
        float p2 = m0.z ? __expf(fast_tanh(sv + k0.z)) : 0.f;
        float p3 = m0.w ? __expf(fast_tanh(sv + k0.w)) : 0.f;
        float p4 = m1.x ? __expf(fast_tanh(sv + k1.x)) : 0.f;
        float p5 = m1.y ? __expf(fast_tanh(sv + k1.y)) : 0.f;
        float p6 = m1.z ? __expf(fast_tanh(sv + k1.z)) : 0.f;
        float p7 = m1.w ? __expf(fast_tanh(sv + k1.w)) : 0.f;
        rowsum += p0 + p1 + p2 + p3 + p4 + p5 + p6 + p7;
        unsigned q0 = pack_bf16x2(p0, p1);
        unsigned q1 = pack_bf16x2(p2, p3);
        unsigned q2 = pack_bf16x2(p4, p5);
        unsigned q3 = pack_bf16x2(p6, p7);
        int gp = gcol ^ (rr & 7);
        *(uint4*)(psrow + 16 * gp) = make_uint4(q0, q1, q2, q3);
    }
    rowsum += __shfl_xor(rowsum, 1, 64);
    rowsum += __shfl_xor(rowsum, 2, 64);
    rowsum += __shfl_xor(rowsum, 4, 64);
    if (seg8 == 0) dinv_lds[r2] = 1.0f / rowsum;

    // ---- B prefetch (only loads in the VMEM queue; no stores yet) ----
    const short* b_base =
        vt_g + (size_t)u * (NJT * 8192) + (32 * w + ln) * 32 + 8 * g;
    bf16x8 pb0[4], pb1[4];
#pragma unroll
    for (int s = 0; s < 4; ++s) {
        int off = (s >> 1) * 8192 + (s & 1) * 4096;
        pb0[s] = *(const bf16x8*)&b_base[off];
        pb1[s] = *(const bf16x8*)&b_base[off + 512];
    }

    // LDS-only barrier
    asm volatile("s_waitcnt lgkmcnt(0)" ::: "memory");
    __builtin_amdgcn_s_barrier();
    asm volatile("" ::: "memory");

    // ---- Phase 3: 16 K-steps, each B-pair feeds BOTH tiles (4 MFMA) ----
    f32x4 a00 = {0.f, 0.f, 0.f, 0.f}, a01 = {0.f, 0.f, 0.f, 0.f};
    f32x4 a10 = {0.f, 0.f, 0.f, 0.f}, a11 = {0.f, 0.f, 0.f, 0.f};
    __builtin_amdgcn_s_setprio(1);
#pragma unroll
    for (int s = 0; s < 16; ++s) {
        int abyte = ln * 1024 + 16 * ((4 * s + g) ^ (ln & 7));
        bf16x8 af0 = *(const bf16x8*)((const char*)ps + abyte);
        bf16x8 af1 = *(const bf16x8*)((const char*)ps + 16384 + abyte);
        a00 = __builtin_amdgcn_mfma_f32_16x16x32_bf16(af0, pb0[s & 3], a00, 0, 0, 0);
        a01 = __builtin_amdgcn_mfma_f32_16x16x32_bf16(af0, pb1[s & 3], a01, 0, 0, 0);
        a10 = __builtin_amdgcn_mfma_f32_16x16x32_bf16(af1, pb0[s & 3], a10, 0, 0, 0);
        a11 = __builtin_amdgcn_mfma_f32_16x16x32_bf16(af1, pb1[s & 3], a11, 0, 0, 0);
        if (s < 12) {
            int off = ((s + 4) >> 1) * 8192 + ((s + 4) & 1) * 4096;
            pb0[s & 3] = *(const bf16x8*)&b_base[off];
            pb1[s & 3] = *(const bf16x8*)&b_base[off + 512];
        }
    }
    __builtin_amdgcn_s_setprio(0);

    // ---- W-frag + u_part prefetch BEFORE attn stores ----
    const short* wbase = wt_g + (32 * w + ln) * 32 + 8 * g;
    bf16x8 wb0[4], wb1[4];
#pragma unroll
    for (int ks = 0; ks < 4; ++ks) {
        wb0[ks] = *(const bf16x8*)&wbase[ks * 4096];
        wb1[ks] = *(const bf16x8*)&wbase[ks * 4096 + 512];
    }
    int c0 = 32 * w + ln, c1 = c0 + 16;
    float up0v = up_g[u * CC + c0];
    float up1v = up_g[u * CC + c1];

    // ---- Phase 2 (late): attn stores, flat coalesced re-read of ps ----
    // NORMAL stores: L2 absorbs the burst; dirty lines may flush after
    // kernel end instead of gating completion (NT forced HBM write-through).
    {
        float* ab = out_attn + ((size_t)(u * II + i0)) * JJ;
#pragma unroll
        for (int k = 0; k < 16; ++k) {
            int f = t + 256 * k;            // [0, 4096) x 4-float chunks
            int row = f >> 7;               // [0, 32)
            int j4 = (f & 127) * 4;         // [0, 512)
            int gcol = j4 >> 3, half = (j4 >> 2) & 1;
            int tl = row >> 4, rw = row & 15;
            uint2 qv = *(const uint2*)((const char*)ps + tl * 16384 + rw * 1024 +
                                       16 * (gcol ^ (rw & 7)) + 8 * half);
            float dv = dinv_lds[row];
            f32x4 v;
            v[0] = __uint_as_float(qv.x << 16) * dv;
            v[1] = __uint_as_float(qv.x & 0xFFFF0000u) * dv;
            v[2] = __uint_as_float(qv.y << 16) * dv;
            v[3] = __uint_as_float(qv.y & 0xFFFF0000u) * dv;
            *(f32x4*)&ab[(size_t)row * JJ + j4] = v;
        }
    }

    // barrier: all ps reads (attn) done -> overlay pooled into ps
    asm volatile("s_waitcnt lgkmcnt(0)" ::: "memory");
    __builtin_amdgcn_s_barrier();
    asm volatile("" ::: "memory");

    // ---- Phase 4: scale by dinv, pack bf16 -> swizzled pooled (overlay) ----
    {
        char* pool = (char*)ps;   // 32 rows x 256B, swizzled granules
#pragma unroll
        for (int ri = 0; ri < 4; ++ri) {
            int row0 = 4 * g + ri, row1 = 16 + row0;
            float dv0 = dinv_lds[row0], dv1 = dinv_lds[row1];
            *(short*)(pool + row0 * 256 + 16 * ((c0 >> 3) ^ (row0 & 7)) +
                      2 * (ln & 7)) = bf16s(a00[ri] * dv0);
            *(short*)(pool + row0 * 256 + 16 * ((c1 >> 3) ^ (row0 & 7)) +
                      2 * (ln & 7)) = bf16s(a01[ri] * dv0);
            *(short*)(pool + row1 * 256 + 16 * ((c0 >> 3) ^ (row1 & 7)) +
                      2 * (ln & 7)) = bf16s(a10[ri] * dv1);
            *(short*)(pool + row1 * 256 + 16 * ((c1 >> 3) ^ (row1 & 7)) +
                      2 * (ln & 7)) = bf16s(a11[ri] * dv1);
        }
    }
    asm volatile("s_waitcnt lgkmcnt(0)" ::: "memory");
    __builtin_amdgcn_s_barrier();
    asm volatile("" ::: "memory");

    // ---- Phase 5: out = relu(u_part + pooled @ W_mlp[E:]) via MFMA ----
    f32x4 o00 = {0.f, 0.f, 0.f, 0.f}, o01 = {0.f, 0.f, 0.f, 0.f};
    f32x4 o10 = {0.f, 0.f, 0.f, 0.f}, o11 = {0.f, 0.f, 0.f, 0.f};
#pragma unroll
    for (int ks = 0; ks < 4; ++ks) {
        int pbyte0 = ln * 256 + 16 * ((4 * ks + g) ^ (ln & 7));
        bf16x8 pa0 = *(const bf16x8*)((const char*)ps + pbyte0);
        bf16x8 pa1 = *(const bf16x8*)((const char*)ps + 4096 + pbyte0);
        o00 = __builtin_amdgcn_mfma_f32_16x16x32_bf16(pa0, wb0[ks], o00, 0, 0, 0);
        o01 = __builtin_amdgcn_mfma_f32_16x16x32_bf16(pa0, wb1[ks], o01, 0, 0, 0);
        o10 = __builtin_amdgcn_mfma_f32_16x16x32_bf16(pa1, wb0[ks], o10, 0, 0, 0);
        o11 = __builtin_amdgcn_mfma_f32_16x16x32_bf16(pa1, wb1[ks], o11, 0, 0, 0);
    }
    {
        float* ctx = out_ctx + ((size_t)(u * II + i0)) * CC;
#pragma unroll
        for (int ri = 0; ri < 4; ++ri) {
            int row0 = 4 * g + ri, row1 = 16 + row0;
            ctx[(size_t)row0 * CC + c0] = fmaxf(o00[ri] + up0v, 0.f);
            ctx[(size_t)row0 * CC + c1] = fmaxf(o01[ri] + up1v, 0.f);
            ctx[(size_t)row1 * CC + c0] = fmaxf(o10[ri] + up0v, 0.f);
            ctx[(size_t)row1 * CC + c1] = fmaxf(o11[ri] + up1v, 0.f);
        }
    }
}

// ---------------------------------------------------------------------------
// Fallback (ws too small): round-2 validated self-contained kernel.
// ---------------------------------------------------------------------------
__global__ __launch_bounds__(256, 3) void fused_fallback(
    const float* __restrict__ tgt, const float* __restrict__ itc,
    const float* __restrict__ user, const int* __restrict__ mask,
    const float* __restrict__ wd, const float* __restrict__ bd,
    const float* __restrict__ Wm, const float* __restrict__ bm,
    float* __restrict__ out_ctx, float* __restrict__ out_attn) {
    __shared__ __align__(16) short Vt[CC][VTP];
    __shared__ __align__(16) float pool[IBF][CC + 4];
    __shared__ __align__(16) float skv[JJ];
    __shared__ __align__(16) float stv[IBF];
    __shared__ __align__(16) float upv[CC];
    __shared__ __align__(16) float dinv_lds[IBF];
    __shared__ unsigned char mk[JJ];

    int b = blockIdx.x;
    int x = b & 7, q = b >> 3;
    int u = x + 8 * (q >> 4);
    int ib = q & 15;
    int i0 = ib * IBF;
    int t = threadIdx.x;

    mk[t] = (unsigned char)(mask[u * JJ + t] != 0);
    mk[t + 256] = (unsigned char)(mask[u * JJ + t + 256] != 0);

    {
        int lane = t & 63, w4 = t >> 6;
        float2 w2 = *(const float2*)&wd[CC + lane * 2];
        for (int r = w4; r < JJ; r += 4) {
            float2 a = *(const float2*)&itc[((size_t)u * JJ + r) * CC + lane * 2];
            float s = wave_reduce_add(a.x * w2.x + a.y * w2.y);
            if (lane == 0) skv[r] = s;
        }
        float2 w1 = *(const float2*)&wd[lane * 2];
        float bdv = bd[0];
        for (int r = w4; r < IBF; r += 4) {
            float2 a = *(const float2*)&tgt[((size_t)u * II + i0 + r) * CC + lane * 2];
            float s = wave_reduce_add(a.x * w1.x + a.y * w1.y);
            if (lane == 0) stv[r] = s + bdv;
        }
        if (t < CC) {
            float acc = bm[t];
            for (int e = 0; e < EE; ++e) acc += user[u * EE + e] * Wm[e * CC + t];
            upv[t] = acc;
        }
    }
    __syncthreads();

    const int l = t & 63;
    const int w = t >> 6;
    const int ln = l & 15;
    const int g = l >> 4;

    bf16x8 a[16];
    float rowsum = 0.0f;
    {
        float s = stv[ln];
#pragma unroll
        for (int t16 = 0; t16 < 16; ++t16) {
            int j = 32 * t16 + 8 * g;
            float4 k0 = *(const float4*)&skv[j];
            float4 k1 = *(const float4*)&skv[j + 4];
            unsigned m0 = *(const unsigned*)&mk[j];
            unsigned m1 = *(const unsigned*)&mk[j + 4];
            float pf[8];
            pf[0] = (m0 & 0x000000FFu) ? __expf(fast_tanh(s + k0.x)) : 0.0f;
            pf[1] = (m0 & 0x0000FF00u) ? __expf(fast_tanh(s + k0.y)) : 0.0f;
            pf[2] = (m0 & 0x00FF0000u) ? __expf(fast_tanh(s + k0.z)) : 0.0f;
            pf[3] = (m0 & 0xFF000000u) ? __expf(fast_tanh(s + k0.w)) : 0.0f;
            pf[4] = (m1 & 0x000000FFu) ? __expf(fast_tanh(s + k1.x)) : 0.0f;
            pf[5] = (m1 & 0x0000FF00u) ? __expf(fast_tanh(s + k1.y)) : 0.0f;
            pf[6] = (m1 & 0x00FF0000u) ? __expf(fast_tanh(s + k1.z)) : 0.0f;
            pf[7] = (m1 & 0xFF000000u) ? __expf(fast_tanh(s + k1.w)) : 0.0f;
            rowsum += pf[0] + pf[1] + pf[2] + pf[3] + pf[4] + pf[5] + pf[6] + pf[7];
            FragU cu;
            cu.u[0] = pack_bf16x2(pf[0], pf[1]);
            cu.u[1] = pack_bf16x2(pf[2], pf[3]);
            cu.u[2] = pack_bf16x2(pf[4], pf[5]);
            cu.u[3] = pack_bf16x2(pf[6], pf[7]);
            a[t16] = cu.v;
        }
    }
    rowsum += __shfl_xor(rowsum, 16, 64);
    rowsum += __shfl_xor(rowsum, 32, 64);
    float dinv = 1.0f / rowsum;
    if (t < 16) dinv_lds[t] = dinv;

    {
        float* abase = out_attn + ((size_t)(u * II + i0 + ln)) * JJ + 8 * g;
#pragma unroll
        for (int t16 = 0; t16 < 16; ++t16) {
            FragU cu; cu.v = a[t16];
            float f0 = __uint_as_float(cu.u[0] << 16) * dinv;
            float f1 = __uint_as_float(cu.u[0] & 0xFFFF0000u) * dinv;
            float f2 = __uint_as_float(cu.u[1] << 16) * dinv;
            float f3 = __uint_as_float(cu.u[1] & 0xFFFF0000u) * dinv;
            float f4 = __uint_as_float(cu.u[2] << 16) * dinv;
            float f5 = __uint_as_float(cu.u[2] & 0xFFFF0000u) * dinv;
            float f6 = __uint_as_float(cu.u[3] << 16) * dinv;
            float f7 = __uint_as_float(cu.u[3] & 0xFFFF0000u) * dinv;
            *(float4*)&abase[32 * t16] = make_float4(f0, f1, f2, f3);
            *(float4*)&abase[32 * t16 + 4] = make_float4(f4, f5, f6, f7);
        }
    }

    f32x4 acc0 = {0.f, 0.f, 0.f, 0.f};
    f32x4 acc1 = {0.f, 0.f, 0.f, 0.f};
    const float* Vu = itc + (size_t)u * JJ * CC;
    const int cg = t & 31;
    const int jp = t >> 5;
    const int n0 = w * 32;

    for (int jt = 0; jt < 8; ++jt) {
        int j0 = jt * JT;
        __syncthreads();
#pragma unroll
        for (int it = 0; it < 4; ++it) {
            int jl = 2 * (jp + 8 * it);
            const float* r0 = &Vu[(size_t)(j0 + jl) * CC];
            const float* r1 = r0 + CC;
#pragma unroll
            for (int qv = 0; qv < 4; ++qv) {
                int c = cg + 32 * qv;
                *(unsigned*)&Vt[c][jl] = pack_bf16x2(r0[c], r1[c]);
            }
        }
        __syncthreads();
#pragma unroll
        for (int kk = 0; kk < 2; ++kk) {
            bf16x8 b0 = *(const bf16x8*)&Vt[n0 + ln][32 * kk + 8 * g];
            bf16x8 b1 = *(const bf16x8*)&Vt[n0 + 16 + ln][32 * kk + 8 * g];
            acc0 = __builtin_amdgcn_mfma_f32_16x16x32_bf16(a[2 * jt + kk], b0,
                                                           acc0, 0, 0, 0);
            acc1 = __builtin_amdgcn_mfma_f32_16x16x32_bf16(a[2 * jt + kk], b1,
                                                           acc1, 0, 0, 0);
        }
    }

    __syncthreads();
    {
        float4 dv = *(const float4*)&dinv_lds[4 * g];
        float dvr[4] = {dv.x, dv.y, dv.z, dv.w};
#pragma unroll
        for (int r = 0; r < 4; ++r) {
            pool[4 * g + r][n0 + ln] = acc0[r] * dvr[r];
            pool[4 * g + r][n0 + 16 + ln] = acc1[r] * dvr[r];
        }
    }
    __syncthreads();

    {
        int tx = t & 15, ty = t >> 4;
        float o[8];
#pragma unroll
        for (int k = 0; k < 8; ++k) o[k] = 0.f;
#pragma unroll 4
        for (int k = 0; k < CC; ++k) {
            float pk = pool[ty][k];
            float4 w0 = *(const float4*)&Wm[(size_t)(EE + k) * CC + tx * 8];
            float4 w1 = *(const float4*)&Wm[(size_t)(EE + k) * CC + tx * 8 + 4];
            o[0] += pk * w0.x; o[1] += pk * w0.y; o[2] += pk * w0.z; o[3] += pk * w0.w;
            o[4] += pk * w1.x; o[5] += pk * w1.y; o[6] += pk * w1.z; o[7] += pk * w1.w;
        }
        float4 up0 = *(const float4*)&upv[tx * 8];
        float4 up1 = *(const float4*)&upv[tx * 8 + 4];
        float4 r0, r1;
        r0.x = fmaxf(o[0] + up0.x, 0.f); r0.y = fmaxf(o[1] + up0.y, 0.f);
        r0.z = fmaxf(o[2] + up0.z, 0.f); r0.w = fmaxf(o[3] + up0.w, 0.f);
        r1.x = fmaxf(o[4] + up1.x, 0.f); r1.y = fmaxf(o[5] + up1.y, 0.f);
        r1.z = fmaxf(o[6] + up1.z, 0.f); r1.w = fmaxf(o[7] + up1.w, 0.f);
        float* ctx = out_ctx + ((size_t)(u * II + i0 + ty)) * CC + tx * 8;
        *(float4*)&ctx[0] = r0;
        *(float4*)&ctx[4] = r1;
    }
}

// ---------------------------------------------------------------------------
extern "C" void kernel_launch(void* const* d_in, const int* in_sizes, int n_in,
                              void* d_out, int out_size, void* d_ws,
                              size_t ws_size, hipStream_t stream) {
    const float* tgt  = (const float*)d_in[0];
    const float* itc  = (const float*)d_in[1];
    const float* user = (const float*)d_in[2];
    const int*   mask = (const int*)d_in[3];
    const float* wd   = (const float*)d_in[4];
    const float* bd   = (const float*)d_in[5];
    const float* Wm   = (const float*)d_in[6];
    const float* bm   = (const float*)d_in[7];
    float* out_ctx  = (float*)d_out;
    float* out_attn = out_ctx + (size_t)UU * II * CC;

    size_t scalars = (size_t)(UU * JJ + UU * CC) * sizeof(float);
    size_t vt_bytes = (size_t)UU * NJT * 8192 * sizeof(short);
    size_t wt_bytes = (size_t)16384 * sizeof(short);
    size_t need = scalars + vt_bytes + wt_bytes;
    if (ws_size >= need) {
        float* sk_g = (float*)d_ws;
        float* up_g = sk_g + UU * JJ;
        short* vt_g = (short*)((char*)d_ws + scalars);
        short* wt_g = vt_g + (size_t)UU * NJT * 8192;
        precompute_kernel<<<PRE_BLOCKS, 256, 0, stream>>>(
            itc, user, wd, Wm, bm, sk_g, up_g, vt_g, wt_g);
        fused_main<<<UU * NIB2, 256, 0, stream>>>(tgt, mask, wd, bd, sk_g, up_g,
                                                  vt_g, wt_g, out_ctx, out_attn);
    } else {
        fused_fallback<<<UU * (II / IBF), 256, 0, stream>>>(
            tgt, itc, user, mask, wd, bd, Wm, bm, out_ctx, out_attn);
    }
}

// Round 15
// 49.498 us; speedup vs baseline: 1.0822x; 1.0822x over previous
//
#include <hip/hip_runtime.h>

// Problem constants (UserContextAttentionPooler): U=128, I=256, J=512, C=E=128
#define UU 128
#define II 256
#define JJ 512
#define CC 128
#define EE 128
#define IB2 32           // i-rows per block (2 MFMA tiles)
#define NIB2 8           // i-blocks per u
#define JT 64            // j per V tile
#define NJT 8            // V tiles per u
#define VTP 72           // (fallback kernel) Vt row stride in shorts
#define IBF 16           // fallback i-rows per block

typedef short bf16x8 __attribute__((ext_vector_type(8)));
typedef float f32x4 __attribute__((ext_vector_type(4)));

union FragU { bf16x8 v; unsigned u[4]; };

__device__ __forceinline__ float fast_tanh(float x) {
    float ex = __expf(2.0f * x);
    return 1.0f - 2.0f / (ex + 1.0f);
}

__device__ __forceinline__ unsigned pack_bf16x2(float lo, float hi) {
    unsigned ul = __float_as_uint(lo), uh = __float_as_uint(hi);
    ul = (ul + 0x7FFFu + ((ul >> 16) & 1u)) >> 16;
    uh = (uh + 0x7FFFu + ((uh >> 16) & 1u)) >> 16;
    return ul | (uh << 16);
}

__device__ __forceinline__ short bf16s(float f) {
    unsigned u = __float_as_uint(f);
    u = (u + 0x7FFFu + ((u >> 16) & 1u)) >> 16;
    return (short)u;
}

__device__ __forceinline__ float wave_reduce_add(float v) {
#pragma unroll
    for (int k = 32; k >= 1; k >>= 1) v += __shfl_xor(v, k, 64);
    return v;
}

// ---------------------------------------------------------------------------
// Kernel A (R9-proven): VT pass (vt_g bf16 B-tiles + s_k; itc read once,
// nontemporal; writer XCD == consumer XCD == u%8), u_part (U,C)[+b_mlp],
// wt_g = bf16 W_mlp[E:] B-frags. Vt tile (u,jt), short idx:
// kk*4096 + c*32 + (j&31); a wave B-frag load is a contiguous 1KB region.
// ---------------------------------------------------------------------------
#define VT_BLOCKS (UU * NJT)      // 1024 (multiple of 8 at offset 0)
#define UP_BLOCKS (UU * CC / 256) // 64

__global__ void precompute_kernel(const float* __restrict__ itc,
                                  const float* __restrict__ user,
                                  const float* __restrict__ wd,
                                  const float* __restrict__ Wm,
                                  const float* __restrict__ bm,
                                  float* __restrict__ sk_g,
                                  float* __restrict__ up_g,
                                  short* __restrict__ vtg,
                                  short* __restrict__ wtg) {
    __shared__ float vt_f[JT][CC + 4];
    int b = blockIdx.x;
    int t = threadIdx.x;
    if (b < VT_BLOCKS) {
        int u = b & 127, jt = b >> 7;   // u fast -> writer XCD = u%8
        const float* src = itc + ((size_t)u * JJ + jt * JT) * CC;
#pragma unroll
        for (int k = 0; k < 8; ++k) {
            int f = t + 256 * k;
            int row = f >> 5, c4 = (f & 31) * 4;
            f32x4 v = __builtin_nontemporal_load(
                (const f32x4*)&src[(size_t)row * CC + c4]);
            *(f32x4*)&vt_f[row][c4] = v;
        }
        __syncthreads();
        {
            int r = t >> 2, q4 = t & 3;
            float s = 0.f;
#pragma unroll
            for (int cc = 0; cc < 32; cc += 4) {
                float4 a = *(const float4*)&vt_f[r][q4 * 32 + cc];
                float4 w = *(const float4*)&wd[CC + q4 * 32 + cc];
                s += a.x * w.x + a.y * w.y + a.z * w.z + a.w * w.w;
            }
            s += __shfl_xor(s, 1, 64);
            s += __shfl_xor(s, 2, 64);
            if (q4 == 0) sk_g[u * JJ + jt * JT + r] = s;
        }
        {
            int c = t & 127, half = t >> 7;
            unsigned* dst = (unsigned*)(vtg + (size_t)(u * NJT + jt) * 8192) +
                            half * 2048 + c * 16;
#pragma unroll
            for (int m4 = 0; m4 < 4; ++m4) {
                unsigned q[4];
#pragma unroll
                for (int mm = 0; mm < 4; ++mm) {
                    int m = 4 * m4 + mm;
                    q[mm] = pack_bf16x2(vt_f[32 * half + 2 * m][c],
                                        vt_f[32 * half + 2 * m + 1][c]);
                }
                *(uint4*)&dst[4 * m4] = make_uint4(q[0], q[1], q[2], q[3]);
            }
        }
    } else if (b < VT_BLOCKS + UP_BLOCKS) {
        int idx = (b - VT_BLOCKS) * 256 + t;
        int u = idx >> 7, c = idx & 127;
        float acc = bm[c];
#pragma unroll 8
        for (int e = 0; e < EE; ++e) acc += user[u * EE + e] * Wm[e * CC + c];
        up_g[idx] = acc;
    } else {
        int n = t & 127, khalf = t >> 7;
#pragma unroll
        for (int ks2 = 0; ks2 < 2; ++ks2) {
            int ks = khalf * 2 + ks2;
#pragma unroll
            for (int g = 0; g < 4; ++g) {
                unsigned q[4];
#pragma unroll
                for (int pr = 0; pr < 4; ++pr) {
                    float lo = Wm[(size_t)(EE + 32 * ks + 8 * g + 2 * pr) * CC + n];
                    float hi = Wm[(size_t)(EE + 32 * ks + 8 * g + 2 * pr + 1) * CC + n];
                    q[pr] = pack_bf16x2(lo, hi);
                }
                *(uint4*)&wtg[ks * 4096 + n * 32 + 8 * g] =
                    make_uint4(q[0], q[1], q[2], q[3]);
            }
        }
    }
}

// ---------------------------------------------------------------------------
// Kernel B (main, R9-proven best): one block per (u, 32-row i-slab) = 2 MFMA
// tiles sharing each B-fragment. 256 threads = 4 waves, 4 blocks/CU. Attn
// stores AFTER the MFMA phase (no stores ahead of B-refills in the vmcnt
// queue), coalesced via flat re-read of ps LDS; pooled overlays ps.
// ---------------------------------------------------------------------------
__global__ __launch_bounds__(256, 4) void fused_main(
    const float* __restrict__ tgt, const int* __restrict__ mask,
    const float* __restrict__ wd, const float* __restrict__ bd,
    const float* __restrict__ sk_g, const float* __restrict__ up_g,
    const short* __restrict__ vt_g, const short* __restrict__ wt_g,
    float* __restrict__ out_ctx, float* __restrict__ out_attn) {
    __shared__ __align__(16) short ps[16384];  // 32KB: 2 swizzled p tiles
    __shared__ float dinv_lds[IB2];

    int b = blockIdx.x;
    int x = b & 7, q = b >> 3;
    int u = x + 8 * (q >> 3);      // 8 blocks of a given u -> same XCD
    int ib = q & 7;
    int i0 = ib * IB2;
    int t = threadIdx.x;
    int w = t >> 6, l = t & 63, ln = l & 15, g = l >> 4;
    int r2 = t >> 3, seg8 = t & 7;  // phase0/1: row [0,32), col-segment [0,8)
    int tile = r2 >> 4, rr = r2 & 15;

    // ---- Phase 0: s_t for row r2 (8 threads/row, 16 floats each; nt) ----
    float sv;
    {
        const float* trow = tgt + ((size_t)(u * II + i0 + r2)) * CC + seg8 * 16;
        f32x4 t0 = __builtin_nontemporal_load((const f32x4*)&trow[0]);
        f32x4 t1 = __builtin_nontemporal_load((const f32x4*)&trow[4]);
        f32x4 t2 = __builtin_nontemporal_load((const f32x4*)&trow[8]);
        f32x4 t3 = __builtin_nontemporal_load((const f32x4*)&trow[12]);
        float4 w0 = *(const float4*)&wd[seg8 * 16];
        float4 w1 = *(const float4*)&wd[seg8 * 16 + 4];
        float4 w2 = *(const float4*)&wd[seg8 * 16 + 8];
        float4 w3 = *(const float4*)&wd[seg8 * 16 + 12];
        float part = t0[0] * w0.x + t0[1] * w0.y + t0[2] * w0.z + t0[3] * w0.w +
                     t1[0] * w1.x + t1[1] * w1.y + t1[2] * w1.z + t1[3] * w1.w +
                     t2[0] * w2.x + t2[1] * w2.y + t2[2] * w2.z + t2[3] * w2.w +
                     t3[0] * w3.x + t3[1] * w3.y + t3[2] * w3.z + t3[3] * w3.w;
        part += __shfl_xor(part, 1, 64);
        part += __shfl_xor(part, 2, 64);
        part += __shfl_xor(part, 4, 64);
        sv = part + bd[0];
    }

    // ---- Phase 1: p; thread handles 64 elems of row r2 (granules seg8+8h) ----
    const float* skb = sk_g + u * JJ;
    const int* mkb = mask + u * JJ;
    char* psrow = (char*)ps + tile * 16384 + rr * 1024;
    float rowsum = 0.f;
#pragma unroll 4
    for (int h = 0; h < 8; ++h) {
        int gcol = seg8 + 8 * h;
        int jb = gcol * 8;
        float4 k0 = *(const float4*)&skb[jb];
        float4 k1 = *(const float4*)&skb[jb + 4];
        int4 m0 = *(const int4*)&mkb[jb];
        int4 m1 = *(const int4*)&mkb[jb + 4];
        float p0 = m0.x ? __expf(fast_tanh(sv + k0.x)) : 0.f;
        float p1 = m0.y ? __expf(fast_tanh(sv + k0.y)) : 0.f;
        float p2 = m0.z ? __expf(fast_tanh(sv + k0.z)) : 0.f;
        float p3 = m0.w ? __expf(fast_tanh(sv + k0.w)) : 0.f;
        float p4 = m1.x ? __expf(fast_tanh(sv + k1.x)) : 0.f;
        float p5 = m1.y ? __expf(fast_tanh(sv + k1.y)) : 0.f;
        float p6 = m1.z ? __expf(fast_tanh(sv + k1.z)) : 0.f;
        float p7 = m1.w ? __expf(fast_tanh(sv + k1.w)) : 0.f;
        rowsum += p0 + p1 + p2 + p3 + p4 + p5 + p6 + p7;
        unsigned q0 = pack_bf16x2(p0, p1);
        unsigned q1 = pack_bf16x2(p2, p3);
        unsigned q2 = pack_bf16x2(p4, p5);
        unsigned q3 = pack_bf16x2(p6, p7);
        int gp = gcol ^ (rr & 7);
        *(uint4*)(psrow + 16 * gp) = make_uint4(q0, q1, q2, q3);
    }
    rowsum += __shfl_xor(rowsum, 1, 64);
    rowsum += __shfl_xor(rowsum, 2, 64);
    rowsum += __shfl_xor(rowsum, 4, 64);
    if (seg8 == 0) dinv_lds[r2] = 1.0f / rowsum;

    // ---- B prefetch (only loads in the VMEM queue; no stores ahead) ----
    const short* b_base =
        vt_g + (size_t)u * (NJT * 8192) + (32 * w + ln) * 32 + 8 * g;
    bf16x8 pb0[4], pb1[4];
#pragma unroll
    for (int s = 0; s < 4; ++s) {
        int off = (s >> 1) * 8192 + (s & 1) * 4096;
        pb0[s] = *(const bf16x8*)&b_base[off];
        pb1[s] = *(const bf16x8*)&b_base[off + 512];
    }

    // LDS-only barrier
    asm volatile("s_waitcnt lgkmcnt(0)" ::: "memory");
    __builtin_amdgcn_s_barrier();
    asm volatile("" ::: "memory");

    // ---- Phase 3: 16 K-steps, each B-pair feeds BOTH tiles (4 MFMA) ----
    f32x4 a00 = {0.f, 0.f, 0.f, 0.f}, a01 = {0.f, 0.f, 0.f, 0.f};
    f32x4 a10 = {0.f, 0.f, 0.f, 0.f}, a11 = {0.f, 0.f, 0.f, 0.f};
    __builtin_amdgcn_s_setprio(1);
#pragma unroll
    for (int s = 0; s < 16; ++s) {
        int abyte = ln * 1024 + 16 * ((4 * s + g) ^ (ln & 7));
        bf16x8 af0 = *(const bf16x8*)((const char*)ps + abyte);
        bf16x8 af1 = *(const bf16x8*)((const char*)ps + 16384 + abyte);
        a00 = __builtin_amdgcn_mfma_f32_16x16x32_bf16(af0, pb0[s & 3], a00, 0, 0, 0);
        a01 = __builtin_amdgcn_mfma_f32_16x16x32_bf16(af0, pb1[s & 3], a01, 0, 0, 0);
        a10 = __builtin_amdgcn_mfma_f32_16x16x32_bf16(af1, pb0[s & 3], a10, 0, 0, 0);
        a11 = __builtin_amdgcn_mfma_f32_16x16x32_bf16(af1, pb1[s & 3], a11, 0, 0, 0);
        if (s < 12) {
            int off = ((s + 4) >> 1) * 8192 + ((s + 4) & 1) * 4096;
            pb0[s & 3] = *(const bf16x8*)&b_base[off];
            pb1[s & 3] = *(const bf16x8*)&b_base[off + 512];
        }
    }
    __builtin_amdgcn_s_setprio(0);

    // ---- Phase 2 (moved): attn stores, flat fully-coalesced re-read of ps ----
    {
        float* ab = out_attn + ((size_t)(u * II + i0)) * JJ;
#pragma unroll
        for (int k = 0; k < 16; ++k) {
            int f = t + 256 * k;            // [0, 4096) x 4-float chunks
            int row = f >> 7;               // [0, 32)
            int j4 = (f & 127) * 4;         // [0, 512)
            int gcol = j4 >> 3, half = (j4 >> 2) & 1;
            int tl = row >> 4, rw = row & 15;
            uint2 qv = *(const uint2*)((const char*)ps + tl * 16384 + rw * 1024 +
                                       16 * (gcol ^ (rw & 7)) + 8 * half);
            float dv = dinv_lds[row];
            f32x4 v;
            v[0] = __uint_as_float(qv.x << 16) * dv;
            v[1] = __uint_as_float(qv.x & 0xFFFF0000u) * dv;
            v[2] = __uint_as_float(qv.y << 16) * dv;
            v[3] = __uint_as_float(qv.y & 0xFFFF0000u) * dv;
            __builtin_nontemporal_store(v, (f32x4*)&ab[(size_t)row * JJ + j4]);
        }
    }

    // ---- W-frag prefetch (L2-hot 32KB; shared by both tiles) ----
    const short* wbase = wt_g + (32 * w + ln) * 32 + 8 * g;
    bf16x8 wb0[4], wb1[4];
#pragma unroll
    for (int ks = 0; ks < 4; ++ks) {
        wb0[ks] = *(const bf16x8*)&wbase[ks * 4096];
        wb1[ks] = *(const bf16x8*)&wbase[ks * 4096 + 512];
    }

    // barrier: all ps reads (attn) done -> overlay pooled into ps
    asm volatile("s_waitcnt lgkmcnt(0)" ::: "memory");
    __builtin_amdgcn_s_barrier();
    asm volatile("" ::: "memory");

    // ---- Phase 4: scale by dinv, pack bf16 -> swizzled pooled (overlay) ----
    {
        char* pool = (char*)ps;   // 32 rows x 256B, swizzled granules
        int c0 = 32 * w + ln, c1 = c0 + 16;
#pragma unroll
        for (int ri = 0; ri < 4; ++ri) {
            int row0 = 4 * g + ri, row1 = 16 + row0;
            float dv0 = dinv_lds[row0], dv1 = dinv_lds[row1];
            *(short*)(pool + row0 * 256 + 16 * ((c0 >> 3) ^ (row0 & 7)) +
                      2 * (ln & 7)) = bf16s(a00[ri] * dv0);
            *(short*)(pool + row0 * 256 + 16 * ((c1 >> 3) ^ (row0 & 7)) +
                      2 * (ln & 7)) = bf16s(a01[ri] * dv0);
            *(short*)(pool + row1 * 256 + 16 * ((c0 >> 3) ^ (row1 & 7)) +
                      2 * (ln & 7)) = bf16s(a10[ri] * dv1);
            *(short*)(pool + row1 * 256 + 16 * ((c1 >> 3) ^ (row1 & 7)) +
                      2 * (ln & 7)) = bf16s(a11[ri] * dv1);
        }
    }
    asm volatile("s_waitcnt lgkmcnt(0)" ::: "memory");
    __builtin_amdgcn_s_barrier();
    asm volatile("" ::: "memory");

    // ---- Phase 5: out = relu(u_part + pooled @ W_mlp[E:]) via MFMA ----
    f32x4 o00 = {0.f, 0.f, 0.f, 0.f}, o01 = {0.f, 0.f, 0.f, 0.f};
    f32x4 o10 = {0.f, 0.f, 0.f, 0.f}, o11 = {0.f, 0.f, 0.f, 0.f};
#pragma unroll
    for (int ks = 0; ks < 4; ++ks) {
        int pbyte0 = ln * 256 + 16 * ((4 * ks + g) ^ (ln & 7));
        bf16x8 pa0 = *(const bf16x8*)((const char*)ps + pbyte0);
        bf16x8 pa1 = *(const bf16x8*)((const char*)ps + 4096 + pbyte0);
        o00 = __builtin_amdgcn_mfma_f32_16x16x32_bf16(pa0, wb0[ks], o00, 0, 0, 0);
        o01 = __builtin_amdgcn_mfma_f32_16x16x32_bf16(pa0, wb1[ks], o01, 0, 0, 0);
        o10 = __builtin_amdgcn_mfma_f32_16x16x32_bf16(pa1, wb0[ks], o10, 0, 0, 0);
        o11 = __builtin_amdgcn_mfma_f32_16x16x32_bf16(pa1, wb1[ks], o11, 0, 0, 0);
    }
    {
        int c0 = 32 * w + ln, c1 = c0 + 16;
        float up0v = up_g[u * CC + c0];
        float up1v = up_g[u * CC + c1];
        float* ctx = out_ctx + ((size_t)(u * II + i0)) * CC;
#pragma unroll
        for (int ri = 0; ri < 4; ++ri) {
            int row0 = 4 * g + ri, row1 = 16 + row0;
            __builtin_nontemporal_store(fmaxf(o00[ri] + up0v, 0.f),
                                        &ctx[(size_t)row0 * CC + c0]);
            __builtin_nontemporal_store(fmaxf(o01[ri] + up1v, 0.f),
                                        &ctx[(size_t)row0 * CC + c1]);
            __builtin_nontemporal_store(fmaxf(o10[ri] + up0v, 0.f),
                                        &ctx[(size_t)row1 * CC + c0]);
            __builtin_nontemporal_store(fmaxf(o11[ri] + up1v, 0.f),
                                        &ctx[(size_t)row1 * CC + c1]);
        }
    }
}

// ---------------------------------------------------------------------------
// Fallback (ws too small): round-2 validated self-contained kernel.
// ---------------------------------------------------------------------------
__global__ __launch_bounds__(256, 3) void fused_fallback(
    const float* __restrict__ tgt, const float* __restrict__ itc,
    const float* __restrict__ user, const int* __restrict__ mask,
    const float* __restrict__ wd, const float* __restrict__ bd,
    const float* __restrict__ Wm, const float* __restrict__ bm,
    float* __restrict__ out_ctx, float* __restrict__ out_attn) {
    __shared__ __align__(16) short Vt[CC][VTP];
    __shared__ __align__(16) float pool[IBF][CC + 4];
    __shared__ __align__(16) float skv[JJ];
    __shared__ __align__(16) float stv[IBF];
    __shared__ __align__(16) float upv[CC];
    __shared__ __align__(16) float dinv_lds[IBF];
    __shared__ unsigned char mk[JJ];

    int b = blockIdx.x;
    int x = b & 7, q = b >> 3;
    int u = x + 8 * (q >> 4);
    int ib = q & 15;
    int i0 = ib * IBF;
    int t = threadIdx.x;

    mk[t] = (unsigned char)(mask[u * JJ + t] != 0);
    mk[t + 256] = (unsigned char)(mask[u * JJ + t + 256] != 0);

    {
        int lane = t & 63, w4 = t >> 6;
        float2 w2 = *(const float2*)&wd[CC + lane * 2];
        for (int r = w4; r < JJ; r += 4) {
            float2 a = *(const float2*)&itc[((size_t)u * JJ + r) * CC + lane * 2];
            float s = wave_reduce_add(a.x * w2.x + a.y * w2.y);
            if (lane == 0) skv[r] = s;
        }
        float2 w1 = *(const float2*)&wd[lane * 2];
        float bdv = bd[0];
        for (int r = w4; r < IBF; r += 4) {
            float2 a = *(const float2*)&tgt[((size_t)u * II + i0 + r) * CC + lane * 2];
            float s = wave_reduce_add(a.x * w1.x + a.y * w1.y);
            if (lane == 0) stv[r] = s + bdv;
        }
        if (t < CC) {
            float acc = bm[t];
            for (int e = 0; e < EE; ++e) acc += user[u * EE + e] * Wm[e * CC + t];
            upv[t] = acc;
        }
    }
    __syncthreads();

    const int l = t & 63;
    const int w = t >> 6;
    const int ln = l & 15;
    const int g = l >> 4;

    bf16x8 a[16];
    float rowsum = 0.0f;
    {
        float s = stv[ln];
#pragma unroll
        for (int t16 = 0; t16 < 16; ++t16) {
            int j = 32 * t16 + 8 * g;
            float4 k0 = *(const float4*)&skv[j];
            float4 k1 = *(const float4*)&skv[j + 4];
            unsigned m0 = *(const unsigned*)&mk[j];
            unsigned m1 = *(const unsigned*)&mk[j + 4];
            float pf[8];
            pf[0] = (m0 & 0x000000FFu) ? __expf(fast_tanh(s + k0.x)) : 0.0f;
            pf[1] = (m0 & 0x0000FF00u) ? __expf(fast_tanh(s + k0.y)) : 0.0f;
            pf[2] = (m0 & 0x00FF0000u) ? __expf(fast_tanh(s + k0.z)) : 0.0f;
            pf[3] = (m0 & 0xFF000000u) ? __expf(fast_tanh(s + k0.w)) : 0.0f;
            pf[4] = (m1 & 0x000000FFu) ? __expf(fast_tanh(s + k1.x)) : 0.0f;
            pf[5] = (m1 & 0x0000FF00u) ? __expf(fast_tanh(s + k1.y)) : 0.0f;
            pf[6] = (m1 & 0x00FF0000u) ? __expf(fast_tanh(s + k1.z)) : 0.0f;
            pf[7] = (m1 & 0xFF000000u) ? __expf(fast_tanh(s + k1.w)) : 0.0f;
            rowsum += pf[0] + pf[1] + pf[2] + pf[3] + pf[4] + pf[5] + pf[6] + pf[7];
            FragU cu;
            cu.u[0] = pack_bf16x2(pf[0], pf[1]);
            cu.u[1] = pack_bf16x2(pf[2], pf[3]);
            cu.u[2] = pack_bf16x2(pf[4], pf[5]);
            cu.u[3] = pack_bf16x2(pf[6], pf[7]);
            a[t16] = cu.v;
        }
    }
    rowsum += __shfl_xor(rowsum, 16, 64);
    rowsum += __shfl_xor(rowsum, 32, 64);
    float dinv = 1.0f / rowsum;
    if (t < 16) dinv_lds[t] = dinv;

    {
        float* abase = out_attn + ((size_t)(u * II + i0 + ln)) * JJ + 8 * g;
#pragma unroll
        for (int t16 = 0; t16 < 16; ++t16) {
            FragU cu; cu.v = a[t16];
            float f0 = __uint_as_float(cu.u[0] << 16) * dinv;
            float f1 = __uint_as_float(cu.u[0] & 0xFFFF0000u) * dinv;
            float f2 = __uint_as_float(cu.u[1] << 16) * dinv;
            float f3 = __uint_as_float(cu.u[1] & 0xFFFF0000u) * dinv;
            float f4 = __uint_as_float(cu.u[2] << 16) * dinv;
            float f5 = __uint_as_float(cu.u[2] & 0xFFFF0000u) * dinv;
            float f6 = __uint_as_float(cu.u[3] << 16) * dinv;
            float f7 = __uint_as_float(cu.u[3] & 0xFFFF0000u) * dinv;
            *(float4*)&abase[32 * t16] = make_float4(f0, f1, f2, f3);
            *(float4*)&abase[32 * t16 + 4] = make_float4(f4, f5, f6, f7);
        }
    }

    f32x4 acc0 = {0.f, 0.f, 0.f, 0.f};
    f32x4 acc1 = {0.f, 0.f, 0.f, 0.f};
    const float* Vu = itc + (size_t)u * JJ * CC;
    const int cg = t & 31;
    const int jp = t >> 5;
    const int n0 = w * 32;

    for (int jt = 0; jt < 8; ++jt) {
        int j0 = jt * JT;
        __syncthreads();
#pragma unroll
        for (int it = 0; it < 4; ++it) {
            int jl = 2 * (jp + 8 * it);
            const float* r0 = &Vu[(size_t)(j0 + jl) * CC];
            const float* r1 = r0 + CC;
#pragma unroll
            for (int qv = 0; qv < 4; ++qv) {
                int c = cg + 32 * qv;
                *(unsigned*)&Vt[c][jl] = pack_bf16x2(r0[c], r1[c]);
            }
        }
        __syncthreads();
#pragma unroll
        for (int kk = 0; kk < 2; ++kk) {
            bf16x8 b0 = *(const bf16x8*)&Vt[n0 + ln][32 * kk + 8 * g];
            bf16x8 b1 = *(const bf16x8*)&Vt[n0 + 16 + ln][32 * kk + 8 * g];
            acc0 = __builtin_amdgcn_mfma_f32_16x16x32_bf16(a[2 * jt + kk], b0,
                                                           acc0, 0, 0, 0);
            acc1 = __builtin_amdgcn_mfma_f32_16x16x32_bf16(a[2 * jt + kk], b1,
                                                           acc1, 0, 0, 0);
        }
    }

    __syncthreads();
    {
        float4 dv = *(const float4*)&dinv_lds[4 * g];
        float dvr[4] = {dv.x, dv.y, dv.z, dv.w};
#pragma unroll
        for (int r = 0; r < 4; ++r) {
            pool[4 * g + r][n0 + ln] = acc0[r] * dvr[r];
            pool[4 * g + r][n0 + 16 + ln] = acc1[r] * dvr[r];
        }
    }
    __syncthreads();

    {
        int tx = t & 15, ty = t >> 4;
        float o[8];
#pragma unroll
        for (int k = 0; k < 8; ++k) o[k] = 0.f;
#pragma unroll 4
        for (int k = 0; k < CC; ++k) {
            float pk = pool[ty][k];
            float4 w0 = *(const float4*)&Wm[(size_t)(EE + k) * CC + tx * 8];
            float4 w1 = *(const float4*)&Wm[(size_t)(EE + k) * CC + tx * 8 + 4];
            o[0] += pk * w0.x; o[1] += pk * w0.y; o[2] += pk * w0.z; o[3] += pk * w0.w;
            o[4] += pk * w1.x; o[5] += pk * w1.y; o[6] += pk * w1.z; o[7] += pk * w1.w;
        }
        float4 up0 = *(const float4*)&upv[tx * 8];
        float4 up1 = *(const float4*)&upv[tx * 8 + 4];
        float4 r0, r1;
        r0.x = fmaxf(o[0] + up0.x, 0.f); r0.y = fmaxf(o[1] + up0.y, 0.f);
        r0.z = fmaxf(o[2] + up0.z, 0.f); r0.w = fmaxf(o[3] + up0.w, 0.f);
        r1.x = fmaxf(o[4] + up1.x, 0.f); r1.y = fmaxf(o[5] + up1.y, 0.f);
        r1.z = fmaxf(o[6] + up1.z, 0.f); r1.w = fmaxf(o[7] + up1.w, 0.f);
        float* ctx = out_ctx + ((size_t)(u * II + i0 + ty)) * CC + tx * 8;
        *(float4*)&ctx[0] = r0;
        *(float4*)&ctx[4] = r1;
    }
}

// ---------------------------------------------------------------------------
extern "C" void kernel_launch(void* const* d_in, const int* in_sizes, int n_in,
                              void* d_out, int out_size, void* d_ws,
                              size_t ws_size, hipStream_t stream) {
    const float* tgt  = (const float*)d_in[0];
    const float* itc  = (const float*)d_in[1];
    const float* user = (const float*)d_in[2];
    const int*   mask = (const int*)d_in[3];
    const float* wd   = (const float*)d_in[4];
    const float* bd   = (const float*)d_in[5];
    const float* Wm   = (const float*)d_in[6];
    const float* bm   = (const float*)d_in[7];
    float* out_ctx  = (float*)d_out;
    float* out_attn = out_ctx + (size_t)UU * II * CC;

    size_t scalars = (size_t)(UU * JJ + UU * CC) * sizeof(float);
    size_t vt_bytes = (size_t)UU * NJT * 8192 * sizeof(short);
    size_t wt_bytes = (size_t)16384 * sizeof(short);
    size_t need = scalars + vt_bytes + wt_bytes;
    if (ws_size >= need) {
        float* sk_g = (float*)d_ws;
        float* up_g = sk_g + UU * JJ;
        short* vt_g = (short*)((char*)d_ws + scalars);
        short* wt_g = vt_g + (size_t)UU * NJT * 8192;
        int gridA = VT_BLOCKS + UP_BLOCKS + 1;
        precompute_kernel<<<gridA, 256, 0, stream>>>(itc, user, wd, Wm, bm,
                                                     sk_g, up_g, vt_g, wt_g);
        fused_main<<<UU * NIB2, 256, 0, stream>>>(tgt, mask, wd, bd, sk_g, up_g,
                                                  vt_g, wt_g, out_ctx, out_attn);
    } else {
        fused_fallback<<<UU * (II / IBF), 256, 0, stream>>>(
            tgt, itc, user, mask, wd, bd, Wm, bm, out_ctx, out_attn);
    }
}

// Round 16
// 49.107 us; speedup vs baseline: 1.0908x; 1.0080x over previous
//
#include <hip/hip_runtime.h>

// Problem constants (UserContextAttentionPooler): U=128, I=256, J=512, C=E=128
#define UU 128
#define II 256
#define JJ 512
#define CC 128
#define EE 128
#define IB2 32           // i-rows per block (2 MFMA tiles)
#define NIB2 8           // i-blocks per u
#define JT 64            // j per V tile
#define NJT 8            // V tiles per u
#define VTP 72           // (fallback kernel) Vt row stride in shorts
#define IBF 16           // fallback i-rows per block

typedef short bf16x8 __attribute__((ext_vector_type(8)));
typedef float f32x4 __attribute__((ext_vector_type(4)));

union FragU { bf16x8 v; unsigned u[4]; };

__device__ __forceinline__ float fast_tanh(float x) {
    float ex = __expf(2.0f * x);
    return 1.0f - 2.0f / (ex + 1.0f);
}

__device__ __forceinline__ unsigned pack_bf16x2(float lo, float hi) {
    unsigned ul = __float_as_uint(lo), uh = __float_as_uint(hi);
    ul = (ul + 0x7FFFu + ((ul >> 16) & 1u)) >> 16;
    uh = (uh + 0x7FFFu + ((uh >> 16) & 1u)) >> 16;
    return ul | (uh << 16);
}

__device__ __forceinline__ short bf16s(float f) {
    unsigned u = __float_as_uint(f);
    u = (u + 0x7FFFu + ((u >> 16) & 1u)) >> 16;
    return (short)u;
}

__device__ __forceinline__ float wave_reduce_add(float v) {
#pragma unroll
    for (int k = 32; k >= 1; k >>= 1) v += __shfl_xor(v, k, 64);
    return v;
}

// ---------------------------------------------------------------------------
// Kernel A (R9-proven): VT pass (vt_g bf16 B-tiles + s_k; itc read once,
// nontemporal; writer XCD == consumer XCD == u%8), u_part (U,C)[+b_mlp],
// wt_g = bf16 W_mlp[E:] B-frags. Vt tile (u,jt), short idx:
// kk*4096 + c*32 + (j&31); a wave B-frag load is a contiguous 1KB region.
// ---------------------------------------------------------------------------
#define VT_BLOCKS (UU * NJT)      // 1024 (multiple of 8 at offset 0)
#define UP_BLOCKS (UU * CC / 256) // 64

__global__ void precompute_kernel(const float* __restrict__ itc,
                                  const float* __restrict__ user,
                                  const float* __restrict__ wd,
                                  const float* __restrict__ Wm,
                                  const float* __restrict__ bm,
                                  float* __restrict__ sk_g,
                                  float* __restrict__ up_g,
                                  short* __restrict__ vtg,
                                  short* __restrict__ wtg) {
    __shared__ float vt_f[JT][CC + 4];
    int b = blockIdx.x;
    int t = threadIdx.x;
    if (b < VT_BLOCKS) {
        int u = b & 127, jt = b >> 7;   // u fast -> writer XCD = u%8
        const float* src = itc + ((size_t)u * JJ + jt * JT) * CC;
#pragma unroll
        for (int k = 0; k < 8; ++k) {
            int f = t + 256 * k;
            int row = f >> 5, c4 = (f & 31) * 4;
            f32x4 v = __builtin_nontemporal_load(
                (const f32x4*)&src[(size_t)row * CC + c4]);
            *(f32x4*)&vt_f[row][c4] = v;
        }
        __syncthreads();
        {
            int r = t >> 2, q4 = t & 3;
            float s = 0.f;
#pragma unroll
            for (int cc = 0; cc < 32; cc += 4) {
                float4 a = *(const float4*)&vt_f[r][q4 * 32 + cc];
                float4 w = *(const float4*)&wd[CC + q4 * 32 + cc];
                s += a.x * w.x + a.y * w.y + a.z * w.z + a.w * w.w;
            }
            s += __shfl_xor(s, 1, 64);
            s += __shfl_xor(s, 2, 64);
            if (q4 == 0) sk_g[u * JJ + jt * JT + r] = s;
        }
        {
            int c = t & 127, half = t >> 7;
            unsigned* dst = (unsigned*)(vtg + (size_t)(u * NJT + jt) * 8192) +
                            half * 2048 + c * 16;
#pragma unroll
            for (int m4 = 0; m4 < 4; ++m4) {
                unsigned q[4];
#pragma unroll
                for (int mm = 0; mm < 4; ++mm) {
                    int m = 4 * m4 + mm;
                    q[mm] = pack_bf16x2(vt_f[32 * half + 2 * m][c],
                                        vt_f[32 * half + 2 * m + 1][c]);
                }
                *(uint4*)&dst[4 * m4] = make_uint4(q[0], q[1], q[2], q[3]);
            }
        }
    } else if (b < VT_BLOCKS + UP_BLOCKS) {
        int idx = (b - VT_BLOCKS) * 256 + t;
        int u = idx >> 7, c = idx & 127;
        float acc = bm[c];
#pragma unroll 8
        for (int e = 0; e < EE; ++e) acc += user[u * EE + e] * Wm[e * CC + c];
        up_g[idx] = acc;
    } else {
        int n = t & 127, khalf = t >> 7;
#pragma unroll
        for (int ks2 = 0; ks2 < 2; ++ks2) {
            int ks = khalf * 2 + ks2;
#pragma unroll
            for (int g = 0; g < 4; ++g) {
                unsigned q[4];
#pragma unroll
                for (int pr = 0; pr < 4; ++pr) {
                    float lo = Wm[(size_t)(EE + 32 * ks + 8 * g + 2 * pr) * CC + n];
                    float hi = Wm[(size_t)(EE + 32 * ks + 8 * g + 2 * pr + 1) * CC + n];
                    q[pr] = pack_bf16x2(lo, hi);
                }
                *(uint4*)&wtg[ks * 4096 + n * 32 + 8 * g] =
                    make_uint4(q[0], q[1], q[2], q[3]);
            }
        }
    }
}

// ---------------------------------------------------------------------------
// Kernel B (main, R9-proven best): one block per (u, 32-row i-slab) = 2 MFMA
// tiles sharing each B-fragment. 256 threads = 4 waves, 4 blocks/CU. Attn
// stores AFTER the MFMA phase (no stores ahead of B-refills in the vmcnt
// queue), coalesced via flat re-read of ps LDS; pooled overlays ps.
// ---------------------------------------------------------------------------
__global__ __launch_bounds__(256, 4) void fused_main(
    const float* __restrict__ tgt, const int* __restrict__ mask,
    const float* __restrict__ wd, const float* __restrict__ bd,
    const float* __restrict__ sk_g, const float* __restrict__ up_g,
    const short* __restrict__ vt_g, const short* __restrict__ wt_g,
    float* __restrict__ out_ctx, float* __restrict__ out_attn) {
    __shared__ __align__(16) short ps[16384];  // 32KB: 2 swizzled p tiles
    __shared__ float dinv_lds[IB2];

    int b = blockIdx.x;
    int x = b & 7, q = b >> 3;
    int u = x + 8 * (q >> 3);      // 8 blocks of a given u -> same XCD
    int ib = q & 7;
    int i0 = ib * IB2;
    int t = threadIdx.x;
    int w = t >> 6, l = t & 63, ln = l & 15, g = l >> 4;
    int r2 = t >> 3, seg8 = t & 7;  // phase0/1: row [0,32), col-segment [0,8)
    int tile = r2 >> 4, rr = r2 & 15;

    // ---- Phase 0: s_t for row r2 (8 threads/row, 16 floats each; nt) ----
    float sv;
    {
        const float* trow = tgt + ((size_t)(u * II + i0 + r2)) * CC + seg8 * 16;
        f32x4 t0 = __builtin_nontemporal_load((const f32x4*)&trow[0]);
        f32x4 t1 = __builtin_nontemporal_load((const f32x4*)&trow[4]);
        f32x4 t2 = __builtin_nontemporal_load((const f32x4*)&trow[8]);
        f32x4 t3 = __builtin_nontemporal_load((const f32x4*)&trow[12]);
        float4 w0 = *(const float4*)&wd[seg8 * 16];
        float4 w1 = *(const float4*)&wd[seg8 * 16 + 4];
        float4 w2 = *(const float4*)&wd[seg8 * 16 + 8];
        float4 w3 = *(const float4*)&wd[seg8 * 16 + 12];
        float part = t0[0] * w0.x + t0[1] * w0.y + t0[2] * w0.z + t0[3] * w0.w +
                     t1[0] * w1.x + t1[1] * w1.y + t1[2] * w1.z + t1[3] * w1.w +
                     t2[0] * w2.x + t2[1] * w2.y + t2[2] * w2.z + t2[3] * w2.w +
                     t3[0] * w3.x + t3[1] * w3.y + t3[2] * w3.z + t3[3] * w3.w;
        part += __shfl_xor(part, 1, 64);
        part += __shfl_xor(part, 2, 64);
        part += __shfl_xor(part, 4, 64);
        sv = part + bd[0];
    }

    // ---- Phase 1: p; thread handles 64 elems of row r2 (granules seg8+8h) ----
    const float* skb = sk_g + u * JJ;
    const int* mkb = mask + u * JJ;
    char* psrow = (char*)ps + tile * 16384 + rr * 1024;
    float rowsum = 0.f;
#pragma unroll 4
    for (int h = 0; h < 8; ++h) {
        int gcol = seg8 + 8 * h;
        int jb = gcol * 8;
        float4 k0 = *(const float4*)&skb[jb];
        float4 k1 = *(const float4*)&skb[jb + 4];
        int4 m0 = *(const int4*)&mkb[jb];
        int4 m1 = *(const int4*)&mkb[jb + 4];
        float p0 = m0.x ? __expf(fast_tanh(sv + k0.x)) : 0.f;
        float p1 = m0.y ? __expf(fast_tanh(sv + k0.y)) : 0.f;
        float p2 = m0.z ? __expf(fast_tanh(sv + k0.z)) : 0.f;
        float p3 = m0.w ? __expf(fast_tanh(sv + k0.w)) : 0.f;
        float p4 = m1.x ? __expf(fast_tanh(sv + k1.x)) : 0.f;
        float p5 = m1.y ? __expf(fast_tanh(sv + k1.y)) : 0.f;
        float p6 = m1.z ? __expf(fast_tanh(sv + k1.z)) : 0.f;
        float p7 = m1.w ? __expf(fast_tanh(sv + k1.w)) : 0.f;
        rowsum += p0 + p1 + p2 + p3 + p4 + p5 + p6 + p7;
        unsigned q0 = pack_bf16x2(p0, p1);
        unsigned q1 = pack_bf16x2(p2, p3);
        unsigned q2 = pack_bf16x2(p4, p5);
        unsigned q3 = pack_bf16x2(p6, p7);
        int gp = gcol ^ (rr & 7);
        *(uint4*)(psrow + 16 * gp) = make_uint4(q0, q1, q2, q3);
    }
    rowsum += __shfl_xor(rowsum, 1, 64);
    rowsum += __shfl_xor(rowsum, 2, 64);
    rowsum += __shfl_xor(rowsum, 4, 64);
    if (seg8 == 0) dinv_lds[r2] = 1.0f / rowsum;

    // ---- B prefetch (only loads in the VMEM queue; no stores ahead) ----
    const short* b_base =
        vt_g + (size_t)u * (NJT * 8192) + (32 * w + ln) * 32 + 8 * g;
    bf16x8 pb0[4], pb1[4];
#pragma unroll
    for (int s = 0; s < 4; ++s) {
        int off = (s >> 1) * 8192 + (s & 1) * 4096;
        pb0[s] = *(const bf16x8*)&b_base[off];
        pb1[s] = *(const bf16x8*)&b_base[off + 512];
    }

    // LDS-only barrier
    asm volatile("s_waitcnt lgkmcnt(0)" ::: "memory");
    __builtin_amdgcn_s_barrier();
    asm volatile("" ::: "memory");

    // ---- Phase 3: 16 K-steps, each B-pair feeds BOTH tiles (4 MFMA) ----
    f32x4 a00 = {0.f, 0.f, 0.f, 0.f}, a01 = {0.f, 0.f, 0.f, 0.f};
    f32x4 a10 = {0.f, 0.f, 0.f, 0.f}, a11 = {0.f, 0.f, 0.f, 0.f};
    __builtin_amdgcn_s_setprio(1);
#pragma unroll
    for (int s = 0; s < 16; ++s) {
        int abyte = ln * 1024 + 16 * ((4 * s + g) ^ (ln & 7));
        bf16x8 af0 = *(const bf16x8*)((const char*)ps + abyte);
        bf16x8 af1 = *(const bf16x8*)((const char*)ps + 16384 + abyte);
        a00 = __builtin_amdgcn_mfma_f32_16x16x32_bf16(af0, pb0[s & 3], a00, 0, 0, 0);
        a01 = __builtin_amdgcn_mfma_f32_16x16x32_bf16(af0, pb1[s & 3], a01, 0, 0, 0);
        a10 = __builtin_amdgcn_mfma_f32_16x16x32_bf16(af1, pb0[s & 3], a10, 0, 0, 0);
        a11 = __builtin_amdgcn_mfma_f32_16x16x32_bf16(af1, pb1[s & 3], a11, 0, 0, 0);
        if (s < 12) {
            int off = ((s + 4) >> 1) * 8192 + ((s + 4) & 1) * 4096;
            pb0[s & 3] = *(const bf16x8*)&b_base[off];
            pb1[s & 3] = *(const bf16x8*)&b_base[off + 512];
        }
    }
    __builtin_amdgcn_s_setprio(0);

    // ---- Phase 2 (moved): attn stores, flat fully-coalesced re-read of ps ----
    {
        float* ab = out_attn + ((size_t)(u * II + i0)) * JJ;
#pragma unroll
        for (int k = 0; k < 16; ++k) {
            int f = t + 256 * k;            // [0, 4096) x 4-float chunks
            int row = f >> 7;               // [0, 32)
            int j4 = (f & 127) * 4;         // [0, 512)
            int gcol = j4 >> 3, half = (j4 >> 2) & 1;
            int tl = row >> 4, rw = row & 15;
            uint2 qv = *(const uint2*)((const char*)ps + tl * 16384 + rw * 1024 +
                                       16 * (gcol ^ (rw & 7)) + 8 * half);
            float dv = dinv_lds[row];
            f32x4 v;
            v[0] = __uint_as_float(qv.x << 16) * dv;
            v[1] = __uint_as_float(qv.x & 0xFFFF0000u) * dv;
            v[2] = __uint_as_float(qv.y << 16) * dv;
            v[3] = __uint_as_float(qv.y & 0xFFFF0000u) * dv;
            __builtin_nontemporal_store(v, (f32x4*)&ab[(size_t)row * JJ + j4]);
        }
    }

    // ---- W-frag prefetch (L2-hot 32KB; shared by both tiles) ----
    const short* wbase = wt_g + (32 * w + ln) * 32 + 8 * g;
    bf16x8 wb0[4], wb1[4];
#pragma unroll
    for (int ks = 0; ks < 4; ++ks) {
        wb0[ks] = *(const bf16x8*)&wbase[ks * 4096];
        wb1[ks] = *(const bf16x8*)&wbase[ks * 4096 + 512];
    }

    // barrier: all ps reads (attn) done -> overlay pooled into ps
    asm volatile("s_waitcnt lgkmcnt(0)" ::: "memory");
    __builtin_amdgcn_s_barrier();
    asm volatile("" ::: "memory");

    // ---- Phase 4: scale by dinv, pack bf16 -> swizzled pooled (overlay) ----
    {
        char* pool = (char*)ps;   // 32 rows x 256B, swizzled granules
        int c0 = 32 * w + ln, c1 = c0 + 16;
#pragma unroll
        for (int ri = 0; ri < 4; ++ri) {
            int row0 = 4 * g + ri, row1 = 16 + row0;
            float dv0 = dinv_lds[row0], dv1 = dinv_lds[row1];
            *(short*)(pool + row0 * 256 + 16 * ((c0 >> 3) ^ (row0 & 7)) +
                      2 * (ln & 7)) = bf16s(a00[ri] * dv0);
            *(short*)(pool + row0 * 256 + 16 * ((c1 >> 3) ^ (row0 & 7)) +
                      2 * (ln & 7)) = bf16s(a01[ri] * dv0);
            *(short*)(pool + row1 * 256 + 16 * ((c0 >> 3) ^ (row1 & 7)) +
                      2 * (ln & 7)) = bf16s(a10[ri] * dv1);
            *(short*)(pool + row1 * 256 + 16 * ((c1 >> 3) ^ (row1 & 7)) +
                      2 * (ln & 7)) = bf16s(a11[ri] * dv1);
        }
    }
    asm volatile("s_waitcnt lgkmcnt(0)" ::: "memory");
    __builtin_amdgcn_s_barrier();
    asm volatile("" ::: "memory");

    // ---- Phase 5: out = relu(u_part + pooled @ W_mlp[E:]) via MFMA ----
    f32x4 o00 = {0.f, 0.f, 0.f, 0.f}, o01 = {0.f, 0.f, 0.f, 0.f};
    f32x4 o10 = {0.f, 0.f, 0.f, 0.f}, o11 = {0.f, 0.f, 0.f, 0.f};
#pragma unroll
    for (int ks = 0; ks < 4; ++ks) {
        int pbyte0 = ln * 256 + 16 * ((4 * ks + g) ^ (ln & 7));
        bf16x8 pa0 = *(const bf16x8*)((const char*)ps + pbyte0);
        bf16x8 pa1 = *(const bf16x8*)((const char*)ps + 4096 + pbyte0);
        o00 = __builtin_amdgcn_mfma_f32_16x16x32_bf16(pa0, wb0[ks], o00, 0, 0, 0);
        o01 = __builtin_amdgcn_mfma_f32_16x16x32_bf16(pa0, wb1[ks], o01, 0, 0, 0);
        o10 = __builtin_amdgcn_mfma_f32_16x16x32_bf16(pa1, wb0[ks], o10, 0, 0, 0);
        o11 = __builtin_amdgcn_mfma_f32_16x16x32_bf16(pa1, wb1[ks], o11, 0, 0, 0);
    }
    {
        int c0 = 32 * w + ln, c1 = c0 + 16;
        float up0v = up_g[u * CC + c0];
        float up1v = up_g[u * CC + c1];
        float* ctx = out_ctx + ((size_t)(u * II + i0)) * CC;
#pragma unroll
        for (int ri = 0; ri < 4; ++ri) {
            int row0 = 4 * g + ri, row1 = 16 + row0;
            __builtin_nontemporal_store(fmaxf(o00[ri] + up0v, 0.f),
                                        &ctx[(size_t)row0 * CC + c0]);
            __builtin_nontemporal_store(fmaxf(o01[ri] + up1v, 0.f),
                                        &ctx[(size_t)row0 * CC + c1]);
            __builtin_nontemporal_store(fmaxf(o10[ri] + up0v, 0.f),
                                        &ctx[(size_t)row1 * CC + c0]);
            __builtin_nontemporal_store(fmaxf(o11[ri] + up1v, 0.f),
                                        &ctx[(size_t)row1 * CC + c1]);
        }
    }
}

// ---------------------------------------------------------------------------
// Fallback (ws too small): round-2 validated self-contained kernel.
// ---------------------------------------------------------------------------
__global__ __launch_bounds__(256, 3) void fused_fallback(
    const float* __restrict__ tgt, const float* __restrict__ itc,
    const float* __restrict__ user, const int* __restrict__ mask,
    const float* __restrict__ wd, const float* __restrict__ bd,
    const float* __restrict__ Wm, const float* __restrict__ bm,
    float* __restrict__ out_ctx, float* __restrict__ out_attn) {
    __shared__ __align__(16) short Vt[CC][VTP];
    __shared__ __align__(16) float pool[IBF][CC + 4];
    __shared__ __align__(16) float skv[JJ];
    __shared__ __align__(16) float stv[IBF];
    __shared__ __align__(16) float upv[CC];
    __shared__ __align__(16) float dinv_lds[IBF];
    __shared__ unsigned char mk[JJ];

    int b = blockIdx.x;
    int x = b & 7, q = b >> 3;
    int u = x + 8 * (q >> 4);
    int ib = q & 15;
    int i0 = ib * IBF;
    int t = threadIdx.x;

    mk[t] = (unsigned char)(mask[u * JJ + t] != 0);
    mk[t + 256] = (unsigned char)(mask[u * JJ + t + 256] != 0);

    {
        int lane = t & 63, w4 = t >> 6;
        float2 w2 = *(const float2*)&wd[CC + lane * 2];
        for (int r = w4; r < JJ; r += 4) {
            float2 a = *(const float2*)&itc[((size_t)u * JJ + r) * CC + lane * 2];
            float s = wave_reduce_add(a.x * w2.x + a.y * w2.y);
            if (lane == 0) skv[r] = s;
        }
        float2 w1 = *(const float2*)&wd[lane * 2];
        float bdv = bd[0];
        for (int r = w4; r < IBF; r += 4) {
            float2 a = *(const float2*)&tgt[((size_t)u * II + i0 + r) * CC + lane * 2];
            float s = wave_reduce_add(a.x * w1.x + a.y * w1.y);
            if (lane == 0) stv[r] = s + bdv;
        }
        if (t < CC) {
            float acc = bm[t];
            for (int e = 0; e < EE; ++e) acc += user[u * EE + e] * Wm[e * CC + t];
            upv[t] = acc;
        }
    }
    __syncthreads();

    const int l = t & 63;
    const int w = t >> 6;
    const int ln = l & 15;
    const int g = l >> 4;

    bf16x8 a[16];
    float rowsum = 0.0f;
    {
        float s = stv[ln];
#pragma unroll
        for (int t16 = 0; t16 < 16; ++t16) {
            int j = 32 * t16 + 8 * g;
            float4 k0 = *(const float4*)&skv[j];
            float4 k1 = *(const float4*)&skv[j + 4];
            unsigned m0 = *(const unsigned*)&mk[j];
            unsigned m1 = *(const unsigned*)&mk[j + 4];
            float pf[8];
            pf[0] = (m0 & 0x000000FFu) ? __expf(fast_tanh(s + k0.x)) : 0.0f;
            pf[1] = (m0 & 0x0000FF00u) ? __expf(fast_tanh(s + k0.y)) : 0.0f;
            pf[2] = (m0 & 0x00FF0000u) ? __expf(fast_tanh(s + k0.z)) : 0.0f;
            pf[3] = (m0 & 0xFF000000u) ? __expf(fast_tanh(s + k0.w)) : 0.0f;
            pf[4] = (m1 & 0x000000FFu) ? __expf(fast_tanh(s + k1.x)) : 0.0f;
            pf[5] = (m1 & 0x0000FF00u) ? __expf(fast_tanh(s + k1.y)) : 0.0f;
            pf[6] = (m1 & 0x00FF0000u) ? __expf(fast_tanh(s + k1.z)) : 0.0f;
            pf[7] = (m1 & 0xFF000000u) ? __expf(fast_tanh(s + k1.w)) : 0.0f;
            rowsum += pf[0] + pf[1] + pf[2] + pf[3] + pf[4] + pf[5] + pf[6] + pf[7];
            FragU cu;
            cu.u[0] = pack_bf16x2(pf[0], pf[1]);
            cu.u[1] = pack_bf16x2(pf[2], pf[3]);
            cu.u[2] = pack_bf16x2(pf[4], pf[5]);
            cu.u[3] = pack_bf16x2(pf[6], pf[7]);
            a[t16] = cu.v;
        }
    }
    rowsum += __shfl_xor(rowsum, 16, 64);
    rowsum += __shfl_xor(rowsum, 32, 64);
    float dinv = 1.0f / rowsum;
    if (t < 16) dinv_lds[t] = dinv;

    {
        float* abase = out_attn + ((size_t)(u * II + i0 + ln)) * JJ + 8 * g;
#pragma unroll
        for (int t16 = 0; t16 < 16; ++t16) {
            FragU cu; cu.v = a[t16];
            float f0 = __uint_as_float(cu.u[0] << 16) * dinv;
            float f1 = __uint_as_float(cu.u[0] & 0xFFFF0000u) * dinv;
            float f2 = __uint_as_float(cu.u[1] << 16) * dinv;
            float f3 = __uint_as_float(cu.u[1] & 0xFFFF0000u) * dinv;
            float f4 = __uint_as_float(cu.u[2] << 16) * dinv;
            float f5 = __uint_as_float(cu.u[2] & 0xFFFF0000u) * dinv;
            float f6 = __uint_as_float(cu.u[3] << 16) * dinv;
            float f7 = __uint_as_float(cu.u[3] & 0xFFFF0000u) * dinv;
            *(float4*)&abase[32 * t16] = make_float4(f0, f1, f2, f3);
            *(float4*)&abase[32 * t16 + 4] = make_float4(f4, f5, f6, f7);
        }
    }

    f32x4 acc0 = {0.f, 0.f, 0.f, 0.f};
    f32x4 acc1 = {0.f, 0.f, 0.f, 0.f};
    const float* Vu = itc + (size_t)u * JJ * CC;
    const int cg = t & 31;
    const int jp = t >> 5;
    const int n0 = w * 32;

    for (int jt = 0; jt < 8; ++jt) {
        int j0 = jt * JT;
        __syncthreads();
#pragma unroll
        for (int it = 0; it < 4; ++it) {
            int jl = 2 * (jp + 8 * it);
            const float* r0 = &Vu[(size_t)(j0 + jl) * CC];
            const float* r1 = r0 + CC;
#pragma unroll
            for (int qv = 0; qv < 4; ++qv) {
                int c = cg + 32 * qv;
                *(unsigned*)&Vt[c][jl] = pack_bf16x2(r0[c], r1[c]);
            }
        }
        __syncthreads();
#pragma unroll
        for (int kk = 0; kk < 2; ++kk) {
            bf16x8 b0 = *(const bf16x8*)&Vt[n0 + ln][32 * kk + 8 * g];
            bf16x8 b1 = *(const bf16x8*)&Vt[n0 + 16 + ln][32 * kk + 8 * g];
            acc0 = __builtin_amdgcn_mfma_f32_16x16x32_bf16(a[2 * jt + kk], b0,
                                                           acc0, 0, 0, 0);
            acc1 = __builtin_amdgcn_mfma_f32_16x16x32_bf16(a[2 * jt + kk], b1,
                                                           acc1, 0, 0, 0);
        }
    }

    __syncthreads();
    {
        float4 dv = *(const float4*)&dinv_lds[4 * g];
        float dvr[4] = {dv.x, dv.y, dv.z, dv.w};
#pragma unroll
        for (int r = 0; r < 4; ++r) {
            pool[4 * g + r][n0 + ln] = acc0[r] * dvr[r];
            pool[4 * g + r][n0 + 16 + ln] = acc1[r] * dvr[r];
        }
    }
    __syncthreads();

    {
        int tx = t & 15, ty = t >> 4;
        float o[8];
#pragma unroll
        for (int k = 0; k < 8; ++k) o[k] = 0.f;
#pragma unroll 4
        for (int k = 0; k < CC; ++k) {
            float pk = pool[ty][k];
            float4 w0 = *(const float4*)&Wm[(size_t)(EE + k) * CC + tx * 8];
            float4 w1 = *(const float4*)&Wm[(size_t)(EE + k) * CC + tx * 8 + 4];
            o[0] += pk * w0.x; o[1] += pk * w0.y; o[2] += pk * w0.z; o[3] += pk * w0.w;
            o[4] += pk * w1.x; o[5] += pk * w1.y; o[6] += pk * w1.z; o[7] += pk * w1.w;
        }
        float4 up0 = *(const float4*)&upv[tx * 8];
        float4 up1 = *(const float4*)&upv[tx * 8 + 4];
        float4 r0, r1;
        r0.x = fmaxf(o[0] + up0.x, 0.f); r0.y = fmaxf(o[1] + up0.y, 0.f);
        r0.z = fmaxf(o[2] + up0.z, 0.f); r0.w = fmaxf(o[3] + up0.w, 0.f);
        r1.x = fmaxf(o[4] + up1.x, 0.f); r1.y = fmaxf(o[5] + up1.y, 0.f);
        r1.z = fmaxf(o[6] + up1.z, 0.f); r1.w = fmaxf(o[7] + up1.w, 0.f);
        float* ctx = out_ctx + ((size_t)(u * II + i0 + ty)) * CC + tx * 8;
        *(float4*)&ctx[0] = r0;
        *(float4*)&ctx[4] = r1;
    }
}

// ---------------------------------------------------------------------------
extern "C" void kernel_launch(void* const* d_in, const int* in_sizes, int n_in,
                              void* d_out, int out_size, void* d_ws,
                              size_t ws_size, hipStream_t stream) {
    const float* tgt  = (const float*)d_in[0];
    const float* itc  = (const float*)d_in[1];
    const float* user = (const float*)d_in[2];
    const int*   mask = (const int*)d_in[3];
    const float* wd   = (const float*)d_in[4];
    const float* bd   = (const float*)d_in[5];
    const float* Wm   = (const float*)d_in[6];
    const float* bm   = (const float*)d_in[7];
    float* out_ctx  = (float*)d_out;
    float* out_attn = out_ctx + (size_t)UU * II * CC;

    size_t scalars = (size_t)(UU * JJ + UU * CC) * sizeof(float);
    size_t vt_bytes = (size_t)UU * NJT * 8192 * sizeof(short);
    size_t wt_bytes = (size_t)16384 * sizeof(short);
    size_t need = scalars + vt_bytes + wt_bytes;
    if (ws_size >= need) {
        float* sk_g = (float*)d_ws;
        float* up_g = sk_g + UU * JJ;
        short* vt_g = (short*)((char*)d_ws + scalars);
        short* wt_g = vt_g + (size_t)UU * NJT * 8192;
        int gridA = VT_BLOCKS + UP_BLOCKS + 1;
        precompute_kernel<<<gridA, 256, 0, stream>>>(itc, user, wd, Wm, bm,
                                                     sk_g, up_g, vt_g, wt_g);
        fused_main<<<UU * NIB2, 256, 0, stream>>>(tgt, mask, wd, bd, sk_g, up_g,
                                                  vt_g, wt_g, out_ctx, out_attn);
    } else {
        fused_fallback<<<UU * (II / IBF), 256, 0, stream>>>(
            tgt, itc, user, mask, wd, bd, Wm, bm, out_ctx, out_attn);
    }
}